// Round 3
// baseline (29292.331 us; speedup 1.0000x reference)
//
#include <hip/hip_runtime.h>

#define BATCH    16384
#define H_DIM    1024
#define D_DIM    512
#define O_DIM    10
#define SEQ      128
#define BM       64
#define NTHREADS 1024   // 16 waves/block, 1 block/CU
#define HSTR     1040   // i8 h row stride (16-B aligned; 4-bank offset -> low-conflict b128)
#define HBUF_SZ  (BM * HSTR)                      // 66560 B per h buffer
#define QW       (127.0f / 0.03125f)              // weight quant scale (bound = 1/sqrt(1024))
#define QSCALE   (0.03125f / (127.0f * 127.0f))   // dequant: acc_i32 -> float

typedef __bf16 bf16;
typedef __bf16 bf16x8 __attribute__((ext_vector_type(8)));
typedef float  f32x16 __attribute__((ext_vector_type(16)));
typedef float  f32x4  __attribute__((ext_vector_type(4)));
typedef int    i32x4  __attribute__((ext_vector_type(4)));
typedef int    i32x16 __attribute__((ext_vector_type(16)));

// ---- static device buffers ----
__device__ bf16        g_x[BATCH * D_DIM];     // 16 MB
__device__ bf16        g_whx[H_DIM * D_DIM];   // 1 MB (phase-0 only)
__device__ signed char g_whhq[H_DIM * H_DIM];  // 1 MB i8 wave-fragment-packed Whh
__device__ bf16        g_wph[O_DIM * H_DIM];   // 20 KB
__device__ float       g_bias[H_DIM];
__device__ float       g_bph[O_DIM];

__device__ __forceinline__ float fast_tanh(float z) {
  float e = __expf(2.0f * z);
  return 1.0f - 2.0f / (e + 1.0f);
}

__global__ void cvt_bf16(const float* __restrict__ src, bf16* __restrict__ dst, int n) {
  const int i = (blockIdx.x * blockDim.x + threadIdx.x) * 8;
  if (i >= n) return;
  f32x4 s0 = *(const f32x4*)(src + i);
  f32x4 s1 = *(const f32x4*)(src + i + 4);
  bf16x8 v;
  #pragma unroll
  for (int j = 0; j < 4; ++j) { v[j] = (bf16)s0[j]; v[4 + j] = (bf16)s1[j]; }
  *(bf16x8*)(dst + i) = v;
}

// pack Whh -> i8 per-wave streams for 16 waves x 2 n-halves x K=32 MFMA:
// dst[t*16+j] with t=(w*32+kc)*2*64 + nt*64 + lane encodes
// Whh[w*64+nt*32+(lane&31)][kc*32+(lane>>5)*16+j], quantized by QW.
__global__ void pack_whhq(const float* __restrict__ src, signed char* __restrict__ dst) {
  const int t = blockIdx.x * blockDim.x + threadIdx.x;   // 0..65535
  const int lane = t & 63;
  const int nt   = (t >> 6) & 1;
  const int kc   = (t >> 7) & 31;
  const int w    = t >> 12;
  const int row = w * 64 + nt * 32 + (lane & 31);
  const int col = kc * 32 + (lane >> 5) * 16;
  const float* s = src + (size_t)row * H_DIM + col;
  #pragma unroll
  for (int j = 0; j < 16; ++j) {
    int q = (int)lrintf(s[j] * QW);
    q = q > 127 ? 127 : (q < -127 ? -127 : q);
    dst[(size_t)t * 16 + j] = (signed char)q;
  }
}

__global__ void cvt_bias(const float* __restrict__ bx, const float* __restrict__ bh,
                         const float* __restrict__ bp) {
  const int i = blockIdx.x * blockDim.x + threadIdx.x;
  if (i < H_DIM) g_bias[i] = bx[i] + bh[i];
  if (i < O_DIM) g_bph[i]  = bp[i];
}

// epilogue macros (all indices compile-time after unroll; rule #20 safe)
#define P0_EPI(ACC, MT)                                                                   \
  _Pragma("unroll")                                                                       \
  for (int r = 0; r < 16; ++r) {                                                          \
    const int row = (MT) * 32 + (r & 3) + 8 * (r >> 2) + 4 * q;                           \
    const int idx = (hh * 2 + (MT)) * 16 + r;                                             \
    const float v = (ACC)[r] + bias;                                                      \
    xq[idx >> 3][idx & 7] = (bf16)v;                                                      \
    hcur[row * HSTR + col] = (signed char)__float2int_rn(fast_tanh(v) * 127.0f);          \
  }

#define ST_EPI(ACC, MT)                                                                   \
  _Pragma("unroll")                                                                       \
  for (int r = 0; r < 16; ++r) {                                                          \
    const int row = (MT) * 32 + (r & 3) + 8 * (r >> 2) + 4 * q;                           \
    const int idx = (hh * 2 + (MT)) * 16 + r;                                             \
    const float v = (float)(ACC)[r] * QSCALE + (float)xq[idx >> 3][idx & 7];              \
    hnxt[row * HSTR + col] = (signed char)__float2int_rn(fast_tanh(v) * 127.0f);          \
  }

// raw barrier: LDS writes made visible (lgkmcnt(0)), but global loads stay in
// flight across it (the whole point -- __syncthreads would drain vmcnt too).
#define LDS_BARRIER()                                      \
  asm volatile("s_waitcnt lgkmcnt(0)" ::: "memory");       \
  __builtin_amdgcn_s_barrier();                            \
  asm volatile("" ::: "memory");

// 256 blocks x 1024 threads, 1 block/CU, wave tile 64x64 processed as 2x 64x32 halves.
// CHANGE vs r2 (4889 us, MfmaUtil 19%, ~55% no-issue cycles): attack serialization.
// (a) raw s_barrier + lgkmcnt-only drain -> B loads live across the step barrier;
// (b) continuous cross-phase B ring (tail of each kc loop prefetches the NEXT
//     phase's first 4 fragments; addresses are step-invariant) -> no cold starts;
// (c) per-wave kc-start stagger (i32 accumulation is exactly commutative) ->
//     breaks the post-barrier LDS read convoy and de-phases B-load bursts;
// (d) s_setprio(1) around the MFMA loop.
__global__ __launch_bounds__(NTHREADS, 4)
void rnn_fused(float* __restrict__ out)
{
  extern __shared__ char smem[];
  signed char* hcur = (signed char*)smem;            // h_t   (read)
  signed char* hnxt = (signed char*)smem + HBUF_SZ;  // h_t+1 (write)

  const int tid  = threadIdx.x;
  const int wave = tid >> 6;    // 0..15
  const int lane = tid & 63;
  const int m31  = lane & 31;
  const int q    = lane >> 5;
  const int r0   = blockIdx.x * BM;
  const int nw0  = wave * 64;   // this wave's 64-col slice
  const int kc0  = (wave & 3) * 8;   // K-ring start stagger (commutative i32 sum)

  const signed char* bstr = g_whhq + (size_t)wave * (32 * 2 * 1024) + lane * 16;

  bf16x8 xq[8];   // resident xW+bias addend: 64 bf16 = 32 VGPRs, live across step loop
  i32x4  bq[4];   // continuous B-fragment ring, lives across phases AND steps

  // ---------------- Phase 0 (bf16): xwb = x @ Whx^T + bias; h1 = q(tanh(xwb)) ----------------
  {
    const bf16* aBase = g_x + (size_t)(r0 + m31) * D_DIM + q * 8;
    #pragma unroll
    for (int hh = 0; hh < 2; ++hh) {
      f32x16 accf0, accf1;
      #pragma unroll
      for (int i = 0; i < 16; ++i) { accf0[i] = 0.0f; accf1[i] = 0.0f; }

      const bf16* bBase = g_whx + (size_t)(nw0 + hh * 32 + m31) * D_DIM + q * 8;
      #pragma unroll 4
      for (int kc = 0; kc < D_DIM / 16; ++kc) {
        bf16x8 a0 = *(const bf16x8*)(aBase + kc * 16);
        bf16x8 a1 = *(const bf16x8*)(aBase + (size_t)32 * D_DIM + kc * 16);
        bf16x8 b  = *(const bf16x8*)(bBase + kc * 16);
        accf0 = __builtin_amdgcn_mfma_f32_32x32x16_bf16(a0, b, accf0, 0, 0, 0);
        accf1 = __builtin_amdgcn_mfma_f32_32x32x16_bf16(a1, b, accf1, 0, 0, 0);
      }

      // ring init for the step loop's first phase (hh=0) -- issue EARLY so the
      // latency hides under this epilogue + barrier.
      if (hh == 1) {
        #pragma unroll
        for (int p = 0; p < 4; ++p)
          bq[p] = *(const i32x4*)(bstr + (((kc0 + p) & 31) * 2 + 0) * 1024);
      }

      const int col = nw0 + hh * 32 + m31;
      const float bias = g_bias[col];
      P0_EPI(accf0, 0)
      P0_EPI(accf1, 1)
    }
  }
  LDS_BARRIER()

  // ---------------- RNN steps 2..SEQ (i8 MFMA, K=32, two col-halves, 1 barrier/step) --------
  const int aoff = m31 * HSTR + q * 16;

  for (int step = 1; step < SEQ; ++step) {
    #pragma unroll
    for (int hh = 0; hh < 2; ++hh) {
      i32x16 acc0, acc1;
      #pragma unroll
      for (int i = 0; i < 16; ++i) { acc0[i] = 0; acc1[i] = 0; }

      const signed char* aP0 = hcur + aoff;
      const signed char* aP1 = aP0 + 32 * HSTR;

      __builtin_amdgcn_s_setprio(1);
      #pragma unroll
      for (int i = 0; i < 32; ++i) {
        const int kci = (kc0 + i) & 31;
        i32x4 a0 = *(const i32x4*)(aP0 + kci * 32);
        i32x4 a1 = *(const i32x4*)(aP1 + kci * 32);
        acc0 = __builtin_amdgcn_mfma_i32_32x32x32_i8(a0, bq[i & 3], acc0, 0, 0, 0);
        acc1 = __builtin_amdgcn_mfma_i32_32x32x32_i8(a1, bq[i & 3], acc1, 0, 0, 0);
        // continuous ring: i<28 prefetches this phase's kc+4; i>=28 prefetches
        // the NEXT phase's first 4 (next step's hh=0 when hh==1 -- same addrs).
        const int kn  = (kc0 + i + 4) & 31;
        const int hxn = (i < 28) ? hh : (hh ^ 1);
        bq[i & 3] = *(const i32x4*)(bstr + (kn * 2 + hxn) * 1024);
      }
      __builtin_amdgcn_s_setprio(0);

      const int col = nw0 + hh * 32 + m31;
      ST_EPI(acc0, 0)
      ST_EPI(acc1, 1)
    }

    LDS_BARRIER()   // hnxt visible; B loads for next step remain in flight
    signed char* t = hcur; hcur = hnxt; hnxt = t;
  }

  // ---------------- Output head: softmax(h @ Wph^T + b), fp32 out ----------------
  {
    const int row  = tid >> 4;   // 0..63
    const int tsub = tid & 15;   // 16 threads per row, k-partitioned
    float p[O_DIM];
    #pragma unroll
    for (int o = 0; o < O_DIM; ++o) p[o] = 0.0f;

    const signed char* hrow = hcur + row * HSTR + tsub * 64;
    for (int kk = 0; kk < 64; kk += 16) {
      i32x4 hp = *(const i32x4*)(hrow + kk);
      float hf[16];
      #pragma unroll
      for (int d = 0; d < 4; ++d)
        #pragma unroll
        for (int j = 0; j < 4; ++j)
          hf[d * 4 + j] = (float)((int)(hp[d] << ((3 - j) * 8)) >> 24);
      #pragma unroll
      for (int o = 0; o < O_DIM; ++o) {
        bf16x8 wv0 = *(const bf16x8*)(g_wph + (size_t)o * H_DIM + tsub * 64 + kk);
        bf16x8 wv1 = *(const bf16x8*)(g_wph + (size_t)o * H_DIM + tsub * 64 + kk + 8);
        #pragma unroll
        for (int j = 0; j < 8; ++j) {
          p[o] += hf[j] * (float)wv0[j];
          p[o] += hf[8 + j] * (float)wv1[j];
        }
      }
    }
    #pragma unroll
    for (int d = 1; d < 16; d <<= 1)
      #pragma unroll
      for (int o = 0; o < O_DIM; ++o) p[o] += __shfl_xor(p[o], d, 16);

    if (tsub == 0) {
      float v[O_DIM], mx = -1e30f;
      #pragma unroll
      for (int o = 0; o < O_DIM; ++o) {
        v[o] = p[o] * (1.0f / 127.0f) + g_bph[o];
        mx = fmaxf(mx, v[o]);
      }
      float s = 0.0f;
      #pragma unroll
      for (int o = 0; o < O_DIM; ++o) { v[o] = __expf(v[o] - mx); s += v[o]; }
      const float inv = 1.0f / s;
      #pragma unroll
      for (int o = 0; o < O_DIM; ++o)
        out[(size_t)(r0 + row) * O_DIM + o] = v[o] * inv;
    }
  }
}

extern "C" void kernel_launch(void* const* d_in, const int* in_sizes, int n_in,
                              void* d_out, int out_size, void* d_ws, size_t ws_size,
                              hipStream_t stream)
{
  (void)d_ws; (void)ws_size; (void)in_sizes; (void)n_in; (void)out_size;
  const float* x     = (const float*)d_in[0];
  const float* Whx_w = (const float*)d_in[1];
  const float* Whx_b = (const float*)d_in[2];
  const float* Whh_w = (const float*)d_in[3];
  const float* Whh_b = (const float*)d_in[4];
  const float* Wph_w = (const float*)d_in[5];
  const float* Wph_b = (const float*)d_in[6];
  float* out = (float*)d_out;

  (void)hipFuncSetAttribute((const void*)rnn_fused,
                            hipFuncAttributeMaxDynamicSharedMemorySize, 2 * HBUF_SZ);

  bf16* gx; bf16* gwhx; signed char* gwhhq; bf16* gwph;
  hipGetSymbolAddress((void**)&gx,    HIP_SYMBOL(g_x));
  hipGetSymbolAddress((void**)&gwhx,  HIP_SYMBOL(g_whx));
  hipGetSymbolAddress((void**)&gwhhq, HIP_SYMBOL(g_whhq));
  hipGetSymbolAddress((void**)&gwph,  HIP_SYMBOL(g_wph));

  cvt_bf16<<<BATCH * D_DIM / 2048, 256, 0, stream>>>(x,     gx,   BATCH * D_DIM);
  cvt_bf16<<<H_DIM * D_DIM / 2048, 256, 0, stream>>>(Whx_w, gwhx, H_DIM * D_DIM);
  pack_whhq<<<65536 / 256, 256, 0, stream>>>(Whh_w, gwhhq);
  cvt_bf16<<<(O_DIM * H_DIM / 8 + 255) / 256, 256, 0, stream>>>(Wph_w, gwph, O_DIM * H_DIM);
  cvt_bias<<<4, 256, 0, stream>>>(Whx_b, Whh_b, Wph_b);

  // plain launch: 256 blocks x 1024 thr, 1 block/CU
  const dim3 grid(BATCH / BM), block(NTHREADS);
  const size_t lds = 2 * HBUF_SZ;   // 133120 B (double-buffered i8 h tile)
  rnn_fused<<<grid, block, lds, stream>>>(out);
}

// Round 4
// 9593.638 us; speedup vs baseline: 3.0533x; 3.0533x over previous
//
#include <hip/hip_runtime.h>

#define BATCH    16384
#define H_DIM    1024
#define D_DIM    512
#define O_DIM    10
#define SEQ      128
#define BM       64
#define NTHREADS 512    // 8 waves/block, 1 block/CU, 256 VGPR/wave budget
#define HSTR     1040   // i8 h row stride (16-B aligned; 65 mod 8 = 1 -> conflict-free b128)
#define HBUF_SZ  (BM * HSTR)                      // 66560 B
#define QW       (127.0f / 0.03125f)              // weight quant scale (bound = 1/sqrt(1024))
#define QSCALE   (0.03125f / (127.0f * 127.0f))   // dequant: acc_i32 -> float

typedef __bf16 bf16;
typedef __bf16 bf16x8 __attribute__((ext_vector_type(8)));
typedef float  f32x16 __attribute__((ext_vector_type(16)));
typedef float  f32x4  __attribute__((ext_vector_type(4)));
typedef int    i32x4  __attribute__((ext_vector_type(4)));
typedef int    i32x16 __attribute__((ext_vector_type(16)));

// ---- static device buffers ----
__device__ bf16        g_x[BATCH * D_DIM];     // 16 MB
__device__ bf16        g_whx[H_DIM * D_DIM];   // 1 MB (phase-0 only)
__device__ signed char g_whhq[H_DIM * H_DIM];  // 1 MB i8 wave-fragment-packed Whh
__device__ bf16        g_wph[O_DIM * H_DIM];   // 20 KB
__device__ float       g_bias[H_DIM];
__device__ float       g_bph[O_DIM];

__device__ __forceinline__ float fast_tanh(float z) {
  float e = __expf(2.0f * z);
  return 1.0f - 2.0f / (e + 1.0f);
}

__global__ void cvt_bf16(const float* __restrict__ src, bf16* __restrict__ dst, int n) {
  const int i = (blockIdx.x * blockDim.x + threadIdx.x) * 8;
  if (i >= n) return;
  f32x4 s0 = *(const f32x4*)(src + i);
  f32x4 s1 = *(const f32x4*)(src + i + 4);
  bf16x8 v;
  #pragma unroll
  for (int j = 0; j < 4; ++j) { v[j] = (bf16)s0[j]; v[4 + j] = (bf16)s1[j]; }
  *(bf16x8*)(dst + i) = v;
}

// pack Whh -> i8 per-wave streams for 8 waves x 4 n-frags x K=32 MFMA:
// dst[t*16+j] with t=((w*32+kc)*4+nt)*64+lane encodes
// Whh[w*128+nt*32+(lane&31)][kc*32+(lane>>5)*16+j], quantized by QW.
__global__ void pack_whhq(const float* __restrict__ src, signed char* __restrict__ dst) {
  const int t = blockIdx.x * blockDim.x + threadIdx.x;   // 0..65535
  const int lane = t & 63;
  const int nt   = (t >> 6) & 3;
  const int kc   = (t >> 8) & 31;
  const int w    = t >> 13;                              // 0..7
  const int row = w * 128 + nt * 32 + (lane & 31);
  const int col = kc * 32 + (lane >> 5) * 16;
  const float* s = src + (size_t)row * H_DIM + col;
  #pragma unroll
  for (int j = 0; j < 16; ++j) {
    int q = (int)lrintf(s[j] * QW);
    q = q > 127 ? 127 : (q < -127 ? -127 : q);
    dst[(size_t)t * 16 + j] = (signed char)q;
  }
}

__global__ void cvt_bias(const float* __restrict__ bx, const float* __restrict__ bh,
                         const float* __restrict__ bp) {
  const int i = blockIdx.x * blockDim.x + threadIdx.x;
  if (i < H_DIM) g_bias[i] = bx[i] + bh[i];
  if (i < O_DIM) g_bph[i]  = bp[i];
}

// raw barrier: LDS writes made visible (lgkmcnt(0)); global B-ring loads for the
// next step stay IN FLIGHT across it (T4). __syncthreads would drain vmcnt too.
#define LDS_BARRIER()                                      \
  asm volatile("s_waitcnt lgkmcnt(0)" ::: "memory");       \
  __builtin_amdgcn_s_barrier();                            \
  asm volatile("" ::: "memory");

// 256 blocks x 512 threads (8 waves), 1 block/CU, wave tile 64x128 (4 n-frags).
// CHANGE vs r1 (4598 us, MfmaUtil 20%): break the 128-reg/wave cap (16-wave block)
// that forced shallow prefetch + per-step xW HBM re-stream. With 256 regs/wave:
// xW+bias resident in 64 VGPRs (phase-0 output, zero per-step global traffic besides
// Whh); continuous even/odd B-ring (named arrays, static nt indexing ONLY -- r3's
// scratch disaster came from a dynamically-indexed ring) whose (kc+2)&31 wrap
// prefetches the next step's first fragments across the lgkm-only barriers;
// A-operand double-buffered in named regs. 2 waves/SIMD; latency hidden by ILP.
__global__ __launch_bounds__(NTHREADS, 2)
void rnn_fused(float* __restrict__ out)
{
  extern __shared__ char smem[];
  signed char* hbuf = (signed char*)smem;   // single 64x1024 i8 h tile (+pad)

  const int tid  = threadIdx.x;
  const int wave = tid >> 6;    // 0..7
  const int lane = tid & 63;
  const int m31  = lane & 31;
  const int q    = lane >> 5;
  const int r0   = blockIdx.x * BM;
  const int nw0  = wave * 128;  // this wave's 128-col slice

  const signed char* bstr = g_whhq + (size_t)wave * 131072 + lane * 16;

  bf16x8 xq[16];   // resident xW+bias: 128 bf16 = 64 VGPRs, live across step loop

  // ---------------- Phase 0 (bf16): xwb = x @ Whx^T + bias; h1 = q(tanh(xwb)) ----------------
  {
    f32x16 accf[2][4];
    #pragma unroll
    for (int mt = 0; mt < 2; ++mt)
      #pragma unroll
      for (int nt = 0; nt < 4; ++nt)
        #pragma unroll
        for (int i = 0; i < 16; ++i) accf[mt][nt][i] = 0.0f;

    const bf16* aBase = g_x + (size_t)(r0 + m31) * D_DIM + q * 8;
    #pragma unroll 4
    for (int kc = 0; kc < D_DIM / 16; ++kc) {
      bf16x8 a0 = *(const bf16x8*)(aBase + kc * 16);
      bf16x8 a1 = *(const bf16x8*)(aBase + (size_t)32 * D_DIM + kc * 16);
      #pragma unroll
      for (int nt = 0; nt < 4; ++nt) {
        bf16x8 b = *(const bf16x8*)(g_whx + (size_t)(nw0 + nt * 32 + m31) * D_DIM + kc * 16 + q * 8);
        accf[0][nt] = __builtin_amdgcn_mfma_f32_32x32x16_bf16(a0, b, accf[0][nt], 0, 0, 0);
        accf[1][nt] = __builtin_amdgcn_mfma_f32_32x32x16_bf16(a1, b, accf[1][nt], 0, 0, 0);
      }
    }

    #pragma unroll
    for (int nt = 0; nt < 4; ++nt) {
      const int col = nw0 + nt * 32 + m31;
      const float bias = g_bias[col];
      #pragma unroll
      for (int mt = 0; mt < 2; ++mt)
        #pragma unroll
        for (int r = 0; r < 16; ++r) {
          const int row = mt * 32 + (r & 3) + 8 * (r >> 2) + 4 * q;  // C/D layout (m74/m101)
          const int idx = (nt * 2 + mt) * 16 + r;
          const float v = accf[mt][nt][r] + bias;
          xq[idx >> 3][idx & 7] = (bf16)v;
          hbuf[row * HSTR + col] = (signed char)__float2int_rn(fast_tanh(v) * 127.0f);
        }
    }
  }

  // B-ring init for step 1 (kc=0 into E, kc=1 into O); loads fly across the barrier
  i32x4 bqE[4], bqO[4];
  #pragma unroll
  for (int nt = 0; nt < 4; ++nt) bqE[nt] = *(const i32x4*)(bstr + (0 * 4 + nt) * 1024);
  #pragma unroll
  for (int nt = 0; nt < 4; ++nt) bqO[nt] = *(const i32x4*)(bstr + (1 * 4 + nt) * 1024);

  LDS_BARRIER()

  // ---------------- RNN steps 2..SEQ (i8 MFMA, K=32) ----------------
  const int aoff = m31 * HSTR + q * 16;

  for (int step = 1; step < SEQ; ++step) {
    i32x16 acc[2][4];
    #pragma unroll
    for (int mt = 0; mt < 2; ++mt)
      #pragma unroll
      for (int nt = 0; nt < 4; ++nt)
        #pragma unroll
        for (int i = 0; i < 16; ++i) acc[mt][nt][i] = 0;

    const signed char* aP0 = hbuf + aoff;
    const signed char* aP1 = aP0 + 32 * HSTR;

    // A-operand pipeline prologue: kc=0 into E regs
    i32x4 aE0 = *(const i32x4*)(aP0);
    i32x4 aE1 = *(const i32x4*)(aP1);

    #pragma unroll
    for (int t = 0; t < 16; ++t) {
      // ---- even kc = 2t ----
      i32x4 aO0 = *(const i32x4*)(aP0 + (2 * t + 1) * 32);
      i32x4 aO1 = *(const i32x4*)(aP1 + (2 * t + 1) * 32);
      #pragma unroll
      for (int nt = 0; nt < 4; ++nt) {
        acc[0][nt] = __builtin_amdgcn_mfma_i32_32x32x32_i8(aE0, bqE[nt], acc[0][nt], 0, 0, 0);
        acc[1][nt] = __builtin_amdgcn_mfma_i32_32x32x32_i8(aE1, bqE[nt], acc[1][nt], 0, 0, 0);
      }
      // prefetch E <- (2t+2)&31 : at t=15 this wraps to kc=0 = NEXT STEP's first
      // fragments (B addresses are step-invariant) -> in flight across the barrier
      #pragma unroll
      for (int nt = 0; nt < 4; ++nt)
        bqE[nt] = *(const i32x4*)(bstr + ((((2 * t + 2) & 31) * 4) + nt) * 1024);

      // ---- odd kc = 2t+1 ----
      if (t < 15) {
        aE0 = *(const i32x4*)(aP0 + (2 * t + 2) * 32);
        aE1 = *(const i32x4*)(aP1 + (2 * t + 2) * 32);
      }
      #pragma unroll
      for (int nt = 0; nt < 4; ++nt) {
        acc[0][nt] = __builtin_amdgcn_mfma_i32_32x32x32_i8(aO0, bqO[nt], acc[0][nt], 0, 0, 0);
        acc[1][nt] = __builtin_amdgcn_mfma_i32_32x32x32_i8(aO1, bqO[nt], acc[1][nt], 0, 0, 0);
      }
      #pragma unroll
      for (int nt = 0; nt < 4; ++nt)
        bqO[nt] = *(const i32x4*)(bstr + ((((2 * t + 3) & 31) * 4) + nt) * 1024);
    }

    LDS_BARRIER()   // all waves done READING hbuf (lgkm drained; B loads in flight)

    #pragma unroll
    for (int nt = 0; nt < 4; ++nt) {
      const int col = nw0 + nt * 32 + m31;
      #pragma unroll
      for (int mt = 0; mt < 2; ++mt)
        #pragma unroll
        for (int r = 0; r < 16; ++r) {
          const int row = mt * 32 + (r & 3) + 8 * (r >> 2) + 4 * q;
          const int idx = (nt * 2 + mt) * 16 + r;
          const float v = (float)acc[mt][nt][r] * QSCALE + (float)xq[idx >> 3][idx & 7];
          hbuf[row * HSTR + col] = (signed char)__float2int_rn(fast_tanh(v) * 127.0f);
        }
    }

    LDS_BARRIER()   // new h visible
  }

  // ---------------- Output head: softmax(h @ Wph^T + b), fp32 out ----------------
  {
    const int row  = tid >> 3;   // 0..63
    const int tsub = tid & 7;    // 8 threads per row, k-partitioned (128 k each)
    float p[O_DIM];
    #pragma unroll
    for (int o = 0; o < O_DIM; ++o) p[o] = 0.0f;

    const signed char* hrow = hbuf + row * HSTR + tsub * 128;
    for (int kk = 0; kk < 128; kk += 16) {
      i32x4 hp = *(const i32x4*)(hrow + kk);
      float hf[16];
      #pragma unroll
      for (int d = 0; d < 4; ++d)
        #pragma unroll
        for (int j = 0; j < 4; ++j)
          hf[d * 4 + j] = (float)((int)(hp[d] << ((3 - j) * 8)) >> 24);
      #pragma unroll
      for (int o = 0; o < O_DIM; ++o) {
        bf16x8 wv0 = *(const bf16x8*)(g_wph + (size_t)o * H_DIM + tsub * 128 + kk);
        bf16x8 wv1 = *(const bf16x8*)(g_wph + (size_t)o * H_DIM + tsub * 128 + kk + 8);
        #pragma unroll
        for (int j = 0; j < 8; ++j) {
          p[o] += hf[j] * (float)wv0[j];
          p[o] += hf[8 + j] * (float)wv1[j];
        }
      }
    }
    #pragma unroll
    for (int d = 1; d < 8; d <<= 1)
      #pragma unroll
      for (int o = 0; o < O_DIM; ++o) p[o] += __shfl_xor(p[o], d, 8);

    if (tsub == 0) {
      float v[O_DIM], mx = -1e30f;
      #pragma unroll
      for (int o = 0; o < O_DIM; ++o) {
        v[o] = p[o] * (1.0f / 127.0f) + g_bph[o];
        mx = fmaxf(mx, v[o]);
      }
      float s = 0.0f;
      #pragma unroll
      for (int o = 0; o < O_DIM; ++o) { v[o] = __expf(v[o] - mx); s += v[o]; }
      const float inv = 1.0f / s;
      #pragma unroll
      for (int o = 0; o < O_DIM; ++o)
        out[(size_t)(r0 + row) * O_DIM + o] = v[o] * inv;
    }
  }
}

extern "C" void kernel_launch(void* const* d_in, const int* in_sizes, int n_in,
                              void* d_out, int out_size, void* d_ws, size_t ws_size,
                              hipStream_t stream)
{
  (void)d_ws; (void)ws_size; (void)in_sizes; (void)n_in; (void)out_size;
  const float* x     = (const float*)d_in[0];
  const float* Whx_w = (const float*)d_in[1];
  const float* Whx_b = (const float*)d_in[2];
  const float* Whh_w = (const float*)d_in[3];
  const float* Whh_b = (const float*)d_in[4];
  const float* Wph_w = (const float*)d_in[5];
  const float* Wph_b = (const float*)d_in[6];
  float* out = (float*)d_out;

  (void)hipFuncSetAttribute((const void*)rnn_fused,
                            hipFuncAttributeMaxDynamicSharedMemorySize, HBUF_SZ);

  bf16* gx; bf16* gwhx; signed char* gwhhq; bf16* gwph;
  hipGetSymbolAddress((void**)&gx,    HIP_SYMBOL(g_x));
  hipGetSymbolAddress((void**)&gwhx,  HIP_SYMBOL(g_whx));
  hipGetSymbolAddress((void**)&gwhhq, HIP_SYMBOL(g_whhq));
  hipGetSymbolAddress((void**)&gwph,  HIP_SYMBOL(g_wph));

  cvt_bf16<<<BATCH * D_DIM / 2048, 256, 0, stream>>>(x,     gx,   BATCH * D_DIM);
  cvt_bf16<<<H_DIM * D_DIM / 2048, 256, 0, stream>>>(Whx_w, gwhx, H_DIM * D_DIM);
  pack_whhq<<<65536 / 256, 256, 0, stream>>>(Whh_w, gwhhq);
  cvt_bf16<<<(O_DIM * H_DIM / 8 + 255) / 256, 256, 0, stream>>>(Wph_w, gwph, O_DIM * H_DIM);
  cvt_bias<<<4, 256, 0, stream>>>(Whx_b, Whh_b, Wph_b);

  // 256 blocks x 512 thr, 1 block/CU, 8 waves
  const dim3 grid(BATCH / BM), block(NTHREADS);
  rnn_fused<<<grid, block, HBUF_SZ, stream>>>(out);
}

// Round 5
// 4615.081 us; speedup vs baseline: 6.3471x; 2.0788x over previous
//
#include <hip/hip_runtime.h>

#define BATCH    16384
#define H_DIM    1024
#define D_DIM    512
#define O_DIM    10
#define SEQ      128
#define BM       64
#define NTHREADS 1024   // 16 waves/block, 1 block/CU
#define HSTR     1040   // i8 h row stride (16-B aligned; 4-bank offset -> low-conflict b128)
#define HBUF_SZ  (BM * HSTR)                      // 66560 B per h buffer
#define QW       (127.0f / 0.03125f)              // weight quant scale (bound = 1/sqrt(1024))
#define QSCALE   (0.03125f / (127.0f * 127.0f))   // dequant: acc_i32 -> float

typedef __bf16 bf16;
typedef __bf16 bf16x8 __attribute__((ext_vector_type(8)));
typedef float  f32x16 __attribute__((ext_vector_type(16)));
typedef float  f32x4  __attribute__((ext_vector_type(4)));
typedef int    i32x4  __attribute__((ext_vector_type(4)));
typedef int    i32x16 __attribute__((ext_vector_type(16)));

// ---- static device buffers ----
__device__ bf16        g_x[BATCH * D_DIM];     // 16 MB
__device__ bf16        g_whx[H_DIM * D_DIM];   // 1 MB (phase-0 only)
__device__ signed char g_whhq[H_DIM * H_DIM];  // 1 MB i8 wave-fragment-packed Whh
__device__ bf16        g_wph[O_DIM * H_DIM];   // 20 KB
__device__ bf16        g_xwp[BATCH * H_DIM];   // 32 MB packed xW+bias (NT stream)
__device__ float       g_bias[H_DIM];
__device__ float       g_bph[O_DIM];

__device__ __forceinline__ float fast_tanh(float z) {
  float e = __expf(2.0f * z);
  return 1.0f - 2.0f / (e + 1.0f);
}

__global__ void cvt_bf16(const float* __restrict__ src, bf16* __restrict__ dst, int n) {
  const int i = (blockIdx.x * blockDim.x + threadIdx.x) * 8;
  if (i >= n) return;
  f32x4 s0 = *(const f32x4*)(src + i);
  f32x4 s1 = *(const f32x4*)(src + i + 4);
  bf16x8 v;
  #pragma unroll
  for (int j = 0; j < 4; ++j) { v[j] = (bf16)s0[j]; v[4 + j] = (bf16)s1[j]; }
  *(bf16x8*)(dst + i) = v;
}

// pack Whh -> i8 per-wave streams for 16 waves x 2 n-frags x K=32 MFMA:
// dst[t*16+j] with t=(w*32+kc)*2*64 + nt*64 + lane encodes
// Whh[w*64+nt*32+(lane&31)][kc*32+(lane>>5)*16+j], quantized by QW.
__global__ void pack_whhq(const float* __restrict__ src, signed char* __restrict__ dst) {
  const int t = blockIdx.x * blockDim.x + threadIdx.x;   // 0..65535
  const int lane = t & 63;
  const int nt   = (t >> 6) & 1;
  const int kc   = (t >> 7) & 31;
  const int w    = t >> 12;
  const int row = w * 64 + nt * 32 + (lane & 31);
  const int col = kc * 32 + (lane >> 5) * 16;
  const float* s = src + (size_t)row * H_DIM + col;
  #pragma unroll
  for (int j = 0; j < 16; ++j) {
    int q = (int)lrintf(s[j] * QW);
    q = q > 127 ? 127 : (q < -127 ? -127 : q);
    dst[(size_t)t * 16 + j] = (signed char)q;
  }
}

__global__ void cvt_bias(const float* __restrict__ bx, const float* __restrict__ bh,
                         const float* __restrict__ bp) {
  const int i = blockIdx.x * blockDim.x + threadIdx.x;
  if (i < H_DIM) g_bias[i] = bx[i] + bh[i];
  if (i < O_DIM) g_bph[i]  = bp[i];
}

#define MFMA4_BF16(A0, A1, B)                                                            \
  accf[0][0] = __builtin_amdgcn_mfma_f32_32x32x16_bf16(A0, (B)[0], accf[0][0], 0, 0, 0); \
  accf[0][1] = __builtin_amdgcn_mfma_f32_32x32x16_bf16(A0, (B)[1], accf[0][1], 0, 0, 0); \
  accf[1][0] = __builtin_amdgcn_mfma_f32_32x32x16_bf16(A1, (B)[0], accf[1][0], 0, 0, 0); \
  accf[1][1] = __builtin_amdgcn_mfma_f32_32x32x16_bf16(A1, (B)[1], accf[1][1], 0, 0, 0);

#define MFMA4_I8(A0, A1, B)                                                              \
  acc[0][0] = __builtin_amdgcn_mfma_i32_32x32x32_i8(A0, (B)[0], acc[0][0], 0, 0, 0);     \
  acc[0][1] = __builtin_amdgcn_mfma_i32_32x32x32_i8(A0, (B)[1], acc[0][1], 0, 0, 0);     \
  acc[1][0] = __builtin_amdgcn_mfma_i32_32x32x32_i8(A1, (B)[0], acc[1][0], 0, 0, 0);     \
  acc[1][1] = __builtin_amdgcn_mfma_i32_32x32x32_i8(A1, (B)[1], acc[1][1], 0, 0, 0);

// raw barrier: LDS reads/writes drained (lgkmcnt(0)) so buffer swap is safe, but
// global loads (B-ring, xW) stay IN FLIGHT across it. __syncthreads drains vmcnt too.
#define LDS_BARRIER()                                      \
  asm volatile("s_waitcnt lgkmcnt(0)" ::: "memory");       \
  __builtin_amdgcn_s_barrier();                            \
  asm volatile("" ::: "memory");

// 256 blocks x 1024 threads, 1 block/CU, wave tile 64x64 -- EXACTLY r1's proven
// decomposition (4598 us). CHANGE vs r1: stall removal only.
// (1) h double-buffered in LDS -> ONE barrier/step (was 2);
// (2) barrier is lgkm-only -> B-ring/xW global loads survive it;
// (3) continuous B-ring: init once, tail prefetch wraps (kc+4)&31 so kc 28..31
//     fetch the NEXT step's first fragments across the barrier -> no cold starts
//     (all register indices static -- r3's scratch lesson);
// (4) one-time vmcnt(0) after phase 0 (NT store->load ordering);
// (5) setprio(1) around the MFMA loop.
__global__ __launch_bounds__(NTHREADS, 3)
void rnn_fused(float* __restrict__ out)
{
  extern __shared__ char smem[];
  signed char* hcur = (signed char*)smem;            // h_t   (read)
  signed char* hnxt = (signed char*)smem + HBUF_SZ;  // h_t+1 (write)

  const int tid  = threadIdx.x;
  const int wave = tid >> 6;    // 0..15
  const int lane = tid & 63;
  const int m31  = lane & 31;
  const int q    = lane >> 5;
  const int r0   = blockIdx.x * BM;
  const int nw0  = wave * 64;   // this wave's 64-col slice

  const signed char* bstr = g_whhq + (size_t)wave * (32 * 2 * 1024) + lane * 16;
  bf16* xbase = g_xwp + ((size_t)blockIdx.x * 16 + wave) * 4096 + lane * 8;

  i32x4 bq[4][2];   // continuous B-fragment ring (static indices only)

  // ---------------- Phase 0 (bf16): xwb = x @ Whx^T + bias; h1 = q(tanh(xwb)) ----------------
  {
    f32x16 accf[2][2];
    #pragma unroll
    for (int mt = 0; mt < 2; ++mt)
      #pragma unroll
      for (int nt = 0; nt < 2; ++nt)
        #pragma unroll
        for (int i = 0; i < 16; ++i) accf[mt][nt][i] = 0.0f;

    const bf16* aBase = g_x + (size_t)(r0 + m31) * D_DIM + q * 8;
    #pragma unroll 4
    for (int kc = 0; kc < D_DIM / 16; ++kc) {
      bf16x8 a0 = *(const bf16x8*)(aBase + kc * 16);
      bf16x8 a1 = *(const bf16x8*)(aBase + (size_t)32 * D_DIM + kc * 16);
      bf16x8 b[2];
      #pragma unroll
      for (int nt = 0; nt < 2; ++nt)
        b[nt] = *(const bf16x8*)(g_whx + (size_t)(nw0 + nt * 32 + m31) * D_DIM + kc * 16 + q * 8);
      MFMA4_BF16(a0, a1, b);
    }

    bf16x8 xq[8];
    #pragma unroll
    for (int nt = 0; nt < 2; ++nt) {
      const int col = nw0 + nt * 32 + m31;
      const float bias = g_bias[col];
      #pragma unroll
      for (int mt = 0; mt < 2; ++mt)
        #pragma unroll
        for (int r = 0; r < 16; ++r) {
          const int row = mt * 32 + (r & 3) + 8 * (r >> 2) + 4 * q;  // C/D layout (m74/m101)
          const int idx = (nt * 2 + mt) * 16 + r;
          const float v = accf[mt][nt][r] + bias;
          xq[idx >> 3][idx & 7] = (bf16)v;
          hcur[row * HSTR + col] = (signed char)__float2int_rn(fast_tanh(v) * 127.0f);
        }
    }
    #pragma unroll
    for (int i = 0; i < 8; ++i)
      __builtin_nontemporal_store(xq[i], (bf16x8*)(xbase + i * 512));
  }

  // NT stores must retire before any step reloads them (barriers no longer drain vmcnt)
  asm volatile("s_waitcnt vmcnt(0)" ::: "memory");

  // B-ring init (kc 0..3); these fly across the barrier and are covered by it
  #pragma unroll
  for (int p = 0; p < 4; ++p)
    #pragma unroll
    for (int nt = 0; nt < 2; ++nt)
      bq[p][nt] = *(const i32x4*)(bstr + (p * 2 + nt) * 1024);

  LDS_BARRIER()

  // ---------------- RNN steps 2..SEQ (i8 MFMA, K=32, 1 barrier/step) ----------------
  const int aoff = m31 * HSTR + q * 16;

  for (int step = 1; step < SEQ; ++step) {
    i32x16 acc[2][2];
    #pragma unroll
    for (int mt = 0; mt < 2; ++mt)
      #pragma unroll
      for (int nt = 0; nt < 2; ++nt)
        #pragma unroll
        for (int i = 0; i < 16; ++i) acc[mt][nt][i] = 0;

    const signed char* aP0 = hcur + aoff;
    const signed char* aP1 = aP0 + 32 * HSTR;

    __builtin_amdgcn_s_setprio(1);
    #pragma unroll
    for (int kc = 0; kc < 32; ++kc) {
      i32x4 a0 = *(const i32x4*)(aP0 + kc * 32);
      i32x4 a1 = *(const i32x4*)(aP1 + kc * 32);
      MFMA4_I8(a0, a1, bq[kc & 3]);
      // continuous ring: kc 28..31 wrap to the NEXT step's kc 0..3 (addresses are
      // step-invariant); loads stay in flight across the lgkm-only barrier.
      #pragma unroll
      for (int nt = 0; nt < 2; ++nt)
        bq[kc & 3][nt] = *(const i32x4*)(bstr + ((((kc + 4) & 31) * 2 + nt) * 1024));
    }
    __builtin_amdgcn_s_setprio(0);

    // xW addend loads (NT); latency partially hidden by other waves' epilogues
    bf16x8 xq[8];
    #pragma unroll
    for (int i = 0; i < 8; ++i)
      xq[i] = __builtin_nontemporal_load((const bf16x8*)(xbase + i * 512));

    #pragma unroll
    for (int nt = 0; nt < 2; ++nt) {
      const int col = nw0 + nt * 32 + m31;
      #pragma unroll
      for (int mt = 0; mt < 2; ++mt)
        #pragma unroll
        for (int r = 0; r < 16; ++r) {
          const int row = mt * 32 + (r & 3) + 8 * (r >> 2) + 4 * q;
          const int idx = (nt * 2 + mt) * 16 + r;
          const float v = (float)acc[mt][nt][r] * QSCALE + (float)xq[idx >> 3][idx & 7];
          hnxt[row * HSTR + col] = (signed char)__float2int_rn(fast_tanh(v) * 127.0f);
        }
    }

    LDS_BARRIER()   // hnxt visible, all hcur reads retired; B loads in flight
    signed char* t = hcur; hcur = hnxt; hnxt = t;
  }

  // ---------------- Output head: softmax(h @ Wph^T + b), fp32 out ----------------
  {
    const int row  = tid >> 4;   // 0..63
    const int tsub = tid & 15;   // 16 threads per row, k-partitioned
    float p[O_DIM];
    #pragma unroll
    for (int o = 0; o < O_DIM; ++o) p[o] = 0.0f;

    const signed char* hrow = hcur + row * HSTR + tsub * 64;
    for (int kk = 0; kk < 64; kk += 16) {
      i32x4 hp = *(const i32x4*)(hrow + kk);
      float hf[16];
      #pragma unroll
      for (int d = 0; d < 4; ++d)
        #pragma unroll
        for (int j = 0; j < 4; ++j)
          hf[d * 4 + j] = (float)((int)(hp[d] << ((3 - j) * 8)) >> 24);
      #pragma unroll
      for (int o = 0; o < O_DIM; ++o) {
        bf16x8 wv0 = *(const bf16x8*)(g_wph + (size_t)o * H_DIM + tsub * 64 + kk);
        bf16x8 wv1 = *(const bf16x8*)(g_wph + (size_t)o * H_DIM + tsub * 64 + kk + 8);
        #pragma unroll
        for (int j = 0; j < 8; ++j) {
          p[o] += hf[j] * (float)wv0[j];
          p[o] += hf[8 + j] * (float)wv1[j];
        }
      }
    }
    #pragma unroll
    for (int d = 1; d < 16; d <<= 1)
      #pragma unroll
      for (int o = 0; o < O_DIM; ++o) p[o] += __shfl_xor(p[o], d, 16);

    if (tsub == 0) {
      float v[O_DIM], mx = -1e30f;
      #pragma unroll
      for (int o = 0; o < O_DIM; ++o) {
        v[o] = p[o] * (1.0f / 127.0f) + g_bph[o];
        mx = fmaxf(mx, v[o]);
      }
      float s = 0.0f;
      #pragma unroll
      for (int o = 0; o < O_DIM; ++o) { v[o] = __expf(v[o] - mx); s += v[o]; }
      const float inv = 1.0f / s;
      #pragma unroll
      for (int o = 0; o < O_DIM; ++o)
        out[(size_t)(r0 + row) * O_DIM + o] = v[o] * inv;
    }
  }
}

extern "C" void kernel_launch(void* const* d_in, const int* in_sizes, int n_in,
                              void* d_out, int out_size, void* d_ws, size_t ws_size,
                              hipStream_t stream)
{
  (void)d_ws; (void)ws_size; (void)in_sizes; (void)n_in; (void)out_size;
  const float* x     = (const float*)d_in[0];
  const float* Whx_w = (const float*)d_in[1];
  const float* Whx_b = (const float*)d_in[2];
  const float* Whh_w = (const float*)d_in[3];
  const float* Whh_b = (const float*)d_in[4];
  const float* Wph_w = (const float*)d_in[5];
  const float* Wph_b = (const float*)d_in[6];
  float* out = (float*)d_out;

  (void)hipFuncSetAttribute((const void*)rnn_fused,
                            hipFuncAttributeMaxDynamicSharedMemorySize, 2 * HBUF_SZ);

  bf16* gx; bf16* gwhx; signed char* gwhhq; bf16* gwph;
  hipGetSymbolAddress((void**)&gx,    HIP_SYMBOL(g_x));
  hipGetSymbolAddress((void**)&gwhx,  HIP_SYMBOL(g_whx));
  hipGetSymbolAddress((void**)&gwhhq, HIP_SYMBOL(g_whhq));
  hipGetSymbolAddress((void**)&gwph,  HIP_SYMBOL(g_wph));

  cvt_bf16<<<BATCH * D_DIM / 2048, 256, 0, stream>>>(x,     gx,   BATCH * D_DIM);
  cvt_bf16<<<H_DIM * D_DIM / 2048, 256, 0, stream>>>(Whx_w, gwhx, H_DIM * D_DIM);
  pack_whhq<<<65536 / 256, 256, 0, stream>>>(Whh_w, gwhhq);
  cvt_bf16<<<(O_DIM * H_DIM / 8 + 255) / 256, 256, 0, stream>>>(Wph_w, gwph, O_DIM * H_DIM);
  cvt_bias<<<4, 256, 0, stream>>>(Whx_b, Whh_b, Wph_b);

  // plain launch: 256 blocks x 1024 thr, 1 block/CU
  const dim3 grid(BATCH / BM), block(NTHREADS);
  const size_t lds = 2 * HBUF_SZ;   // 133120 B (double-buffered i8 h tile)
  rnn_fused<<<grid, block, lds, stream>>>(out);
}